// Round 1
// baseline (167.733 us; speedup 1.0000x reference)
//
#include <hip/hip_runtime.h>
#include <stdint.h>
#include <stddef.h>

// ---------------- types ----------------
typedef __bf16 bf16_t;
typedef bf16_t bf16x4v __attribute__((ext_vector_type(4)));
typedef bf16_t bf16x8v __attribute__((ext_vector_type(8)));
typedef float  f32x4   __attribute__((ext_vector_type(4)));

#define NBATCH 8
#define SEQ    2048
#define DIM    512
#define SP     2052   // padded seq (mult of 12)
#define NB2    1026
#define NB3    684
#define NB4    513
#define NL     512    // output rows per batch (SEQ/4)

static __device__ __forceinline__ f32x4 ldbf4(const bf16_t* p) {
  bf16x4v v = *(const bf16x4v*)p;
  f32x4 r;
  r.x = (float)v[0]; r.y = (float)v[1]; r.z = (float)v[2]; r.w = (float)v[3];
  return r;
}
static __device__ __forceinline__ void stbf4(bf16_t* p, f32x4 v) {
  bf16x4v o;
  o[0] = (bf16_t)v.x; o[1] = (bf16_t)v.y; o[2] = (bf16_t)v.z; o[3] = (bf16_t)v.w;
  *(bf16x4v*)p = o;
}

static __device__ __forceinline__ void gload_lds16(const void* g, void* l) {
  __builtin_amdgcn_global_load_lds(
      (const __attribute__((address_space(1))) void*)g,
      (__attribute__((address_space(3))) void*)l, 16, 0, 0);
}

// ---------------- k0a: pw_w -> bf16 transposed (N,K) ----------------
__global__ __launch_bounds__(256) void k0_wt(const float* __restrict__ pw,
                                             bf16_t* __restrict__ Wt) {
  int idx = blockIdx.x * 256 + threadIdx.x;   // 0..262143
  int n = idx >> 9, k = idx & 511;
  Wt[(size_t)n * DIM + k] = (bf16_t)pw[(size_t)k * DIM + n];
}

// ---------------- k0b: mask -> float 0/1, padded to SP ----------------
__global__ __launch_bounds__(256) void k0_mask(const void* __restrict__ mraw,
                                               float* __restrict__ mask01) {
  int idx = blockIdx.x * 256 + threadIdx.x;
  if (idx >= NBATCH * SP) return;
  int b = idx / SP, s = idx - b * SP;
  // detect upload format: bytes at offset%4!=0 nonzero => 1-byte bools
  const unsigned char* mb = (const unsigned char*)mraw;
  int u8 = 0;
#pragma unroll
  for (int i = 0; i < 64; i++)
    if ((i & 3) != 0 && mb[i] != 0) u8 = 1;
  float v = 0.f;
  if (s < SEQ) {
    int mi = b * SEQ + s;
    int nz = u8 ? (mb[mi] != 0) : (((const int*)mraw)[mi] != 0);
    v = nz ? 1.f : 0.f;
  }
  mask01[idx] = v;
}

// ---------------- k1: A = depthwise conv of emb[x], bf16 ----------------
__global__ __launch_bounds__(128) void k1_build_a(
    const int* __restrict__ x, const float* __restrict__ emb,
    const float* __restrict__ dww, const float* __restrict__ dwb,
    bf16_t* __restrict__ A) {
  int row = blockIdx.x;            // 0..16383
  int b = row >> 11, s = row & 2047;
  int d0 = threadIdx.x * 4;
  f32x4 acc = *(const f32x4*)(dwb + d0);
#pragma unroll
  for (int t = 0; t < 4; t++) {
    int sp = s + t;
    if (sp < SEQ) {
      int v = x[b * SEQ + sp];
      f32x4 e = *(const f32x4*)(emb + (size_t)v * DIM + d0);
      f32x4 w = *(const f32x4*)(dww + t * DIM + d0);
      acc += e * w;
    }
  }
  stbf4(A + (size_t)row * DIM + d0, acc);
}

// ---------------- k2: H = A @ Wt^T + pw_b  (bf16 MFMA, B^T layout) ------
#define BM 128
#define BN 128
#define BK 32
__global__ __launch_bounds__(256) void k2_gemm(
    const bf16_t* __restrict__ A, const bf16_t* __restrict__ Bt,
    const float* __restrict__ bias, bf16_t* __restrict__ H) {
  __shared__ __align__(16) bf16_t As[BM * BK];
  __shared__ __align__(16) bf16_t Bs[BN * BK];
  const int t = threadIdx.x;
  const int m0 = blockIdx.x * BM, n0 = blockIdx.y * BN;
  const int lane = t & 63, wave = t >> 6;
  const int wm = (wave >> 1) * 64, wn = (wave & 1) * 64;
  const int mloc = lane & 15, quad = lane >> 4;

  f32x4 acc[4][4] = {};

  const int i1 = t, i2 = t + 256;               // 16B segment ids (0..511)
  char* asd1 = (char*)As + i1 * 16;
  char* asd2 = (char*)As + i2 * 16;
  char* bsd1 = (char*)Bs + i1 * 16;
  char* bsd2 = (char*)Bs + i2 * 16;
  const int ar1 = i1 >> 2, ak1 = (i1 & 3) * 8;  // row, k-offset (elements)
  const int ar2 = i2 >> 2, ak2 = (i2 & 3) * 8;

  for (int k0 = 0; k0 < 512; k0 += BK) {
    gload_lds16(A + (size_t)(m0 + ar1) * DIM + k0 + ak1, asd1);
    gload_lds16(A + (size_t)(m0 + ar2) * DIM + k0 + ak2, asd2);
    gload_lds16(Bt + (size_t)(n0 + ar1) * DIM + k0 + ak1, bsd1);
    gload_lds16(Bt + (size_t)(n0 + ar2) * DIM + k0 + ak2, bsd2);
    __syncthreads();
    bf16x8v af[4], bfr[4];
#pragma unroll
    for (int i = 0; i < 4; i++)
      af[i] = *(const bf16x8v*)&As[(wm + i * 16 + mloc) * BK + quad * 8];
#pragma unroll
    for (int i = 0; i < 4; i++)
      bfr[i] = *(const bf16x8v*)&Bs[(wn + i * 16 + mloc) * BK + quad * 8];
#pragma unroll
    for (int mi = 0; mi < 4; mi++)
#pragma unroll
      for (int ni = 0; ni < 4; ni++)
        acc[mi][ni] = __builtin_amdgcn_mfma_f32_16x16x32_bf16(
            af[mi], bfr[ni], acc[mi][ni], 0, 0, 0);
    __syncthreads();
  }
#pragma unroll
  for (int ni = 0; ni < 4; ni++) {
    int col = n0 + wn + ni * 16 + mloc;
    float bv = bias[col];
#pragma unroll
    for (int mi = 0; mi < 4; mi++) {
      int rbase = m0 + wm + mi * 16 + quad * 4;
#pragma unroll
      for (int r = 0; r < 4; r++)
        H[(size_t)(rbase + r) * DIM + col] = (bf16_t)(acc[mi][ni][r] + bv);
    }
  }
}

// ---------------- k3: level means R2/R3/R4 + block scores ----------------
__global__ __launch_bounds__(128) void k3_levels(
    const bf16_t* __restrict__ H, const float* __restrict__ mask01,
    const float* __restrict__ sw, const float* __restrict__ sbp,
    bf16_t* __restrict__ R2, bf16_t* __restrict__ R3, bf16_t* __restrict__ R4,
    float* __restrict__ sc1, float* __restrict__ sc2,
    float* __restrict__ sc3, float* __restrict__ sc4) {
  const int b = blockIdx.x, c = blockIdx.y;   // c: 0..170
  const int s0 = c * 12;
  const int t = threadIdx.x;
  const int d0 = t * 4;
  const float sb = sbp[0];

  f32x4 h[12];
  float ms[12], p[12];
  f32x4 swv = *(const f32x4*)(sw + d0);
#pragma unroll
  for (int i = 0; i < 12; i++) {
    int s = s0 + i;
    ms[i] = mask01[b * SP + s];
    if (s < SEQ) {
      h[i] = ldbf4(H + ((size_t)b * SEQ + s) * DIM + d0);
    } else {
      h[i].x = h[i].y = h[i].z = h[i].w = 0.f;
    }
    p[i] = h[i].x * swv.x + h[i].y * swv.y + h[i].z * swv.z + h[i].w * swv.w;
  }
  // level means (bf16 out)
#pragma unroll
  for (int j = 0; j < 6; j++) {
    int i0 = 2 * j;
    float cc = ms[i0] + ms[i0 + 1];
    f32x4 sm = h[i0] * ms[i0] + h[i0 + 1] * ms[i0 + 1];
    float sc = cc > 0.f ? 1.f / cc : 0.f;
    stbf4(R2 + ((size_t)b * NB2 + (c * 6 + j)) * DIM + d0, sm * sc);
  }
#pragma unroll
  for (int j = 0; j < 4; j++) {
    int i0 = 3 * j;
    float cc = ms[i0] + ms[i0 + 1] + ms[i0 + 2];
    f32x4 sm = h[i0] * ms[i0] + h[i0 + 1] * ms[i0 + 1] + h[i0 + 2] * ms[i0 + 2];
    float sc = cc > 0.f ? 1.f / cc : 0.f;
    stbf4(R3 + ((size_t)b * NB3 + (c * 4 + j)) * DIM + d0, sm * sc);
  }
#pragma unroll
  for (int j = 0; j < 3; j++) {
    int i0 = 4 * j;
    float cc = ms[i0] + ms[i0 + 1] + ms[i0 + 2] + ms[i0 + 3];
    f32x4 sm = h[i0] * ms[i0] + h[i0 + 1] * ms[i0 + 1] +
               h[i0 + 2] * ms[i0 + 2] + h[i0 + 3] * ms[i0 + 3];
    float sc = cc > 0.f ? 1.f / cc : 0.f;
    stbf4(R4 + ((size_t)b * NB4 + (c * 3 + j)) * DIM + d0, sm * sc);
  }
  // reduce hs = H[s]·score_w across 128 threads (2 waves)
#pragma unroll
  for (int off = 32; off > 0; off >>= 1)
#pragma unroll
    for (int i = 0; i < 12; i++) p[i] += __shfl_down(p[i], off);
  __shared__ float hsw[2][12];
  int lane = t & 63, wv = t >> 6;
  if (lane == 0)
#pragma unroll
    for (int i = 0; i < 12; i++) hsw[wv][i] = p[i];
  __syncthreads();
#define HSUM(i) (hsw[0][i] + hsw[1][i])
  if (t < 12) sc1[b * SP + s0 + t] = HSUM(t) * ms[t] + sb;
  if (t < 6) {
    int i0 = 2 * t;
    float cc = ms[i0] + ms[i0 + 1];
    float s2 = HSUM(i0) * ms[i0] + HSUM(i0 + 1) * ms[i0 + 1];
    sc2[b * NB2 + c * 6 + t] = (cc > 0.f ? s2 / cc : 0.f) + sb;
  }
  if (t < 4) {
    int i0 = 3 * t;
    float cc = ms[i0] + ms[i0 + 1] + ms[i0 + 2];
    float s3 = HSUM(i0) * ms[i0] + HSUM(i0 + 1) * ms[i0 + 1] + HSUM(i0 + 2) * ms[i0 + 2];
    sc3[b * NB3 + c * 4 + t] = (cc > 0.f ? s3 / cc : 0.f) + sb;
  }
  if (t < 3) {
    int i0 = 4 * t;
    float cc = ms[i0] + ms[i0 + 1] + ms[i0 + 2] + ms[i0 + 3];
    float s4 = HSUM(i0) * ms[i0] + HSUM(i0 + 1) * ms[i0 + 1] +
               HSUM(i0 + 2) * ms[i0 + 2] + HSUM(i0 + 3) * ms[i0 + 3];
    sc4[b * NB4 + c * 3 + t] = (cc > 0.f ? s4 / cc : 0.f) + sb;
  }
#undef HSUM
}

// ---------------- k4: per-position level softmax -> P ----------------
__global__ __launch_bounds__(256) void k4_p(
    const float* __restrict__ mask01, const float* __restrict__ sc1,
    const float* __restrict__ sc2, const float* __restrict__ sc3,
    const float* __restrict__ sc4, float* __restrict__ P) {
  int idx = blockIdx.x * 256 + threadIdx.x;
  if (idx >= NBATCH * SP) return;
  int b = idx / SP, s = idx - b * SP;
  const float* mb = mask01 + b * SP;
  float m1 = mb[s];
  int j2 = s >> 1;
  float m2 = fmaxf(mb[2 * j2], mb[2 * j2 + 1]);
  int j3 = s / 3, s3 = 3 * j3;
  float m3 = fmaxf(fmaxf(mb[s3], mb[s3 + 1]), mb[s3 + 2]);
  int j4 = s >> 2, s4 = 4 * j4;
  float m4 = fmaxf(fmaxf(mb[s4], mb[s4 + 1]), fmaxf(mb[s4 + 2], mb[s4 + 3]));
  float v1 = sc1[b * SP + s], v2 = sc2[b * NB2 + j2];
  float v3 = sc3[b * NB3 + j3], v4 = sc4[b * NB4 + j4];
  const float NEG = -3.0e38f;
  float a1 = m1 > 0.f ? v1 : NEG, a2 = m2 > 0.f ? v2 : NEG;
  float a3 = m3 > 0.f ? v3 : NEG, a4 = m4 > 0.f ? v4 : NEG;
  float mx = fmaxf(fmaxf(a1, a2), fmaxf(a3, a4));
  f32x4 o;
  if (mx <= NEG) {
    o.x = o.y = o.z = o.w = 0.25f;  // all-masked: jax gives uniform (unused downstream)
  } else {
    float e1 = m1 > 0.f ? __expf(v1 - mx) : 0.f;
    float e2 = m2 > 0.f ? __expf(v2 - mx) : 0.f;
    float e3 = m3 > 0.f ? __expf(v3 - mx) : 0.f;
    float e4 = m4 > 0.f ? __expf(v4 - mx) : 0.f;
    float inv = 1.f / (e1 + e2 + e3 + e4);
    o.x = e1 * inv; o.y = e2 * inv; o.z = e3 * inv; o.w = e4 * inv;
  }
  *(f32x4*)(P + (size_t)idx * 4) = o;
}

// ---------------- k5: seq attention (dim 4), j-chunked partials ---------
__global__ __launch_bounds__(128) void k5_attn(
    const float* __restrict__ P, const float* __restrict__ mask01,
    float* __restrict__ Wacc) {
  const int b = blockIdx.x, it = blockIdx.y, jc = blockIdx.z;
  const int t = threadIdx.x;
  __shared__ f32x4 Q[513];
  __shared__ float Mf[513];
  const int j0 = jc * 513;
  for (int j = t; j < 513; j += 128) {
    Q[j] = *(const f32x4*)(P + ((size_t)b * SP + j0 + j) * 4);
    Mf[j] = mask01[b * SP + j0 + j];
  }
  __syncthreads();
  const int i = it * 128 + t;  // 0..2047
  f32x4 qi = *(const f32x4*)(P + ((size_t)b * SP + i) * 4);
  float den = 0.f;
  f32x4 acc; acc.x = acc.y = acc.z = acc.w = 0.f;
  // sim = qi·pj ∈ [0,1] (dots of softmax vectors) -> no max subtraction needed
  for (int j = 0; j < 513; j++) {
    f32x4 pj = Q[j];
    float sim = qi.x * pj.x + qi.y * pj.y + qi.z * pj.z + qi.w * pj.w;
    float e = Mf[j] * __expf(sim);
    den += e;
    acc += e * pj;
  }
  float* wp = Wacc + (((size_t)jc * NBATCH + b) * SEQ + i) * 5;
  wp[0] = acc.x; wp[1] = acc.y; wp[2] = acc.z; wp[3] = acc.w; wp[4] = den;
}

// ---------------- k6: combine + weighted reprs + chunk mean -------------
__global__ __launch_bounds__(128) void k6_out(
    const bf16_t* __restrict__ H, const bf16_t* __restrict__ R2,
    const bf16_t* __restrict__ R3, const bf16_t* __restrict__ R4,
    const float* __restrict__ mask01, const float* __restrict__ Wacc,
    float* __restrict__ out, float* __restrict__ omask) {
  const int b = blockIdx.x, l = blockIdx.y;
  const int t = threadIdx.x;
  const int d0 = t * 4;
  __shared__ f32x4 wsh[4];
  __shared__ float msh[4];
  if (t < 4) {
    int s = l * 4 + t;
    float n0 = 0, n1 = 0, n2 = 0, n3 = 0, dn = 0;
#pragma unroll
    for (int jc = 0; jc < 4; jc++) {
      const float* wp = Wacc + (((size_t)jc * NBATCH + b) * SEQ + s) * 5;
      n0 += wp[0]; n1 += wp[1]; n2 += wp[2]; n3 += wp[3]; dn += wp[4];
    }
    float inv = dn > 0.f ? 1.f / dn : 0.f;
    f32x4 w; w.x = n0 * inv; w.y = n1 * inv; w.z = n2 * inv; w.w = n3 * inv;
    wsh[t] = w;
    msh[t] = mask01[b * SP + s];
  }
  __syncthreads();
  f32x4 o; o.x = o.y = o.z = o.w = 0.f;
  float cnt = 0.f;
#pragma unroll
  for (int si = 0; si < 4; si++) {
    int s = l * 4 + si;
    float m = msh[si];
    f32x4 w = wsh[si];
    f32x4 r1 = ldbf4(H + ((size_t)b * SEQ + s) * DIM + d0);
    f32x4 r2 = ldbf4(R2 + ((size_t)b * NB2 + (s >> 1)) * DIM + d0);
    f32x4 r3 = ldbf4(R3 + ((size_t)b * NB3 + (s / 3)) * DIM + d0);
    f32x4 r4 = ldbf4(R4 + ((size_t)b * NB4 + (s >> 2)) * DIM + d0);
    o += m * (w.x * r1 + w.y * r2 + w.z * r3 + w.w * r4);
    cnt += m;
  }
  float inv = cnt > 0.f ? 1.f / cnt : 0.f;
  o *= inv;
  *(f32x4*)(out + ((size_t)b * NL + l) * DIM + d0) = o;
  if (t == 0) omask[b * NL + l] = cnt > 0.f ? 1.f : 0.f;
}

// ---------------- launch ----------------
extern "C" void kernel_launch(void* const* d_in, const int* in_sizes, int n_in,
                              void* d_out, int out_size, void* d_ws, size_t ws_size,
                              hipStream_t stream) {
  const int*   x    = (const int*)d_in[0];
  const void*  mraw = d_in[1];
  const float* emb  = (const float*)d_in[2];
  const float* dww  = (const float*)d_in[3];
  const float* dwb  = (const float*)d_in[4];
  const float* pw   = (const float*)d_in[5];
  const float* pwb  = (const float*)d_in[6];
  const float* sw   = (const float*)d_in[7];
  const float* sb   = (const float*)d_in[8];

  char* ws = (char*)d_ws;
  size_t off = 0;
  auto alloc = [&](size_t bytes) {
    size_t o = off;
    off = (off + bytes + 255) & ~(size_t)255;
    return o;
  };
  bf16_t* A    = (bf16_t*)(ws + alloc((size_t)NBATCH * SEQ * DIM * 2));
  bf16_t* H    = (bf16_t*)(ws + alloc((size_t)NBATCH * SEQ * DIM * 2));
  bf16_t* Wt   = (bf16_t*)(ws + alloc((size_t)DIM * DIM * 2));
  bf16_t* R2   = (bf16_t*)(ws + alloc((size_t)NBATCH * NB2 * DIM * 2));
  bf16_t* R3   = (bf16_t*)(ws + alloc((size_t)NBATCH * NB3 * DIM * 2));
  bf16_t* R4   = (bf16_t*)(ws + alloc((size_t)NBATCH * NB4 * DIM * 2));
  float* mask01 = (float*)(ws + alloc((size_t)NBATCH * SP * 4));
  float* sc1   = (float*)(ws + alloc((size_t)NBATCH * SP * 4));
  float* sc2   = (float*)(ws + alloc((size_t)NBATCH * NB2 * 4));
  float* sc3   = (float*)(ws + alloc((size_t)NBATCH * NB3 * 4));
  float* sc4   = (float*)(ws + alloc((size_t)NBATCH * NB4 * 4));
  float* P     = (float*)(ws + alloc((size_t)NBATCH * SP * 4 * 4));
  float* Wacc  = (float*)(ws + alloc((size_t)4 * NBATCH * SEQ * 5 * 4));

  float* out   = (float*)d_out;
  float* omask = out + (size_t)NBATCH * NL * DIM;

  k0_wt  <<<1024, 256, 0, stream>>>(pw, Wt);
  k0_mask<<<(NBATCH * SP + 255) / 256, 256, 0, stream>>>(mraw, mask01);
  k1_build_a<<<NBATCH * SEQ, 128, 0, stream>>>(x, emb, dww, dwb, A);
  k2_gemm<<<dim3(128, 4), 256, 0, stream>>>(A, Wt, pwb, H);
  k3_levels<<<dim3(NBATCH, 171), 128, 0, stream>>>(H, mask01, sw, sb,
                                                   R2, R3, R4, sc1, sc2, sc3, sc4);
  k4_p<<<(NBATCH * SP + 255) / 256, 256, 0, stream>>>(mask01, sc1, sc2, sc3, sc4, P);
  k5_attn<<<dim3(NBATCH, 16, 4), 128, 0, stream>>>(P, mask01, Wacc);
  k6_out<<<dim3(NBATCH, NL), 128, 0, stream>>>(H, R2, R3, R4, mask01, Wacc,
                                               out, omask);
}

// Round 2
// 142.909 us; speedup vs baseline: 1.1737x; 1.1737x over previous
//
#include <hip/hip_runtime.h>
#include <stdint.h>
#include <stddef.h>

// ---------------- types ----------------
typedef __bf16 bf16_t;
typedef bf16_t bf16x4v __attribute__((ext_vector_type(4)));
typedef bf16_t bf16x8v __attribute__((ext_vector_type(8)));
typedef float  f32x4   __attribute__((ext_vector_type(4)));

#define NBATCH 8
#define SEQ    2048
#define DIM    512
#define SP     2052   // padded seq (mult of 12)
#define NB2    1026
#define NB3    684
#define NB4    513
#define NL     512    // output rows per batch (SEQ/4)
#define NJC    8      // k5 j-chunks
#define JCH    257    // ceil(SP/NJC)

static __device__ __forceinline__ f32x4 ldbf4(const bf16_t* p) {
  bf16x4v v = *(const bf16x4v*)p;
  f32x4 r;
  r.x = (float)v[0]; r.y = (float)v[1]; r.z = (float)v[2]; r.w = (float)v[3];
  return r;
}
static __device__ __forceinline__ void stbf4(bf16_t* p, f32x4 v) {
  bf16x4v o;
  o[0] = (bf16_t)v.x; o[1] = (bf16_t)v.y; o[2] = (bf16_t)v.z; o[3] = (bf16_t)v.w;
  *(bf16x4v*)p = o;
}

static __device__ __forceinline__ void gload_lds16(const void* g, void* l) {
  __builtin_amdgcn_global_load_lds(
      (const __attribute__((address_space(1))) void*)g,
      (__attribute__((address_space(3))) void*)l, 16, 0, 0);
}

// ---------------- kA: fused Wt transpose + mask normalize + depthwise A --
#define GA_WT   1024                       // 262144 / 256
#define GA_MASK 65                         // ceil(8*2052 / 256)
#define GA_A    (NBATCH * SEQ / 2)         // 8192 blocks, 2 rows each
__global__ __launch_bounds__(256) void kA_prep(
    const float* __restrict__ pw, bf16_t* __restrict__ Wt,
    const void* __restrict__ mraw, float* __restrict__ mask01,
    const int* __restrict__ x, const float* __restrict__ emb,
    const float* __restrict__ dww, const float* __restrict__ dwb,
    bf16_t* __restrict__ A) {
  const int bx = blockIdx.x, t = threadIdx.x;
  if (bx < GA_WT) {
    int idx = bx * 256 + t;
    int n = idx >> 9, k = idx & 511;
    Wt[(size_t)n * DIM + k] = (bf16_t)pw[(size_t)k * DIM + n];
    return;
  }
  if (bx < GA_WT + GA_MASK) {
    int idx = (bx - GA_WT) * 256 + t;
    if (idx >= NBATCH * SP) return;
    int b = idx / SP, s = idx - b * SP;
    const unsigned char* mb = (const unsigned char*)mraw;
    int u8 = 0;
#pragma unroll
    for (int i = 0; i < 64; i++)
      if ((i & 3) != 0 && mb[i] != 0) u8 = 1;
    float v = 0.f;
    if (s < SEQ) {
      int mi = b * SEQ + s;
      int nz = u8 ? (mb[mi] != 0) : (((const int*)mraw)[mi] != 0);
      v = nz ? 1.f : 0.f;
    }
    mask01[idx] = v;
    return;
  }
  // depthwise conv: 2 rows per block
  int rp = bx - (GA_WT + GA_MASK);
  int row = rp * 2 + (t >> 7);             // 0..16383
  int b = row >> 11, s = row & 2047;
  int d0 = (t & 127) * 4;
  f32x4 acc = *(const f32x4*)(dwb + d0);
#pragma unroll
  for (int tt = 0; tt < 4; tt++) {
    int sp = s + tt;
    if (sp < SEQ) {
      int v = x[b * SEQ + sp];
      f32x4 e = *(const f32x4*)(emb + (size_t)v * DIM + d0);
      f32x4 w = *(const f32x4*)(dww + tt * DIM + d0);
      acc += e * w;
    }
  }
  stbf4(A + (size_t)row * DIM + d0, acc);
}

// ---------------- k2: H = A @ Wt^T + pw_b  (bf16 MFMA, XCD-swizzled) ----
#define BM 128
#define BN 128
#define BK 32
__global__ __launch_bounds__(256) void k2_gemm(
    const bf16_t* __restrict__ A, const bf16_t* __restrict__ Bt,
    const float* __restrict__ bias, bf16_t* __restrict__ H) {
  __shared__ __align__(16) bf16_t As[BM * BK];
  __shared__ __align__(16) bf16_t Bs[BN * BK];
  const int t = threadIdx.x;
  // XCD-aware swizzle: 512 blocks, round-robin b->XCD b&7. Keep the 4
  // n-blocks of one m-tile on the same XCD so A-tile re-reads hit its L2.
  const int bid = blockIdx.x;
  const int xcd = bid & 7, loc = bid >> 3;       // loc 0..63
  const int mt = xcd * 16 + (loc >> 2);          // 0..127
  const int nt = loc & 3;                        // 0..3
  const int m0 = mt * BM, n0 = nt * BN;
  const int lane = t & 63, wave = t >> 6;
  const int wm = (wave >> 1) * 64, wn = (wave & 1) * 64;
  const int mloc = lane & 15, quad = lane >> 4;

  f32x4 acc[4][4] = {};

  const int i1 = t, i2 = t + 256;               // 16B segment ids (0..511)
  char* asd1 = (char*)As + i1 * 16;
  char* asd2 = (char*)As + i2 * 16;
  char* bsd1 = (char*)Bs + i1 * 16;
  char* bsd2 = (char*)Bs + i2 * 16;
  const int ar1 = i1 >> 2, ak1 = (i1 & 3) * 8;
  const int ar2 = i2 >> 2, ak2 = (i2 & 3) * 8;

  for (int k0 = 0; k0 < 512; k0 += BK) {
    gload_lds16(A + (size_t)(m0 + ar1) * DIM + k0 + ak1, asd1);
    gload_lds16(A + (size_t)(m0 + ar2) * DIM + k0 + ak2, asd2);
    gload_lds16(Bt + (size_t)(n0 + ar1) * DIM + k0 + ak1, bsd1);
    gload_lds16(Bt + (size_t)(n0 + ar2) * DIM + k0 + ak2, bsd2);
    __syncthreads();
    bf16x8v af[4], bfr[4];
#pragma unroll
    for (int i = 0; i < 4; i++)
      af[i] = *(const bf16x8v*)&As[(wm + i * 16 + mloc) * BK + quad * 8];
#pragma unroll
    for (int i = 0; i < 4; i++)
      bfr[i] = *(const bf16x8v*)&Bs[(wn + i * 16 + mloc) * BK + quad * 8];
#pragma unroll
    for (int mi = 0; mi < 4; mi++)
#pragma unroll
      for (int ni = 0; ni < 4; ni++)
        acc[mi][ni] = __builtin_amdgcn_mfma_f32_16x16x32_bf16(
            af[mi], bfr[ni], acc[mi][ni], 0, 0, 0);
    __syncthreads();
  }
#pragma unroll
  for (int ni = 0; ni < 4; ni++) {
    int col = n0 + wn + ni * 16 + mloc;
    float bv = bias[col];
#pragma unroll
    for (int mi = 0; mi < 4; mi++) {
      int rbase = m0 + wm + mi * 16 + quad * 4;
#pragma unroll
      for (int r = 0; r < 4; r++)
        H[(size_t)(rbase + r) * DIM + col] = (bf16_t)(acc[mi][ni][r] + bv);
    }
  }
}

// ---------------- kB: level means R2/R3/R4 + block scores + P softmax ----
__global__ __launch_bounds__(128) void kB_levels(
    const bf16_t* __restrict__ H, const float* __restrict__ mask01,
    const float* __restrict__ sw, const float* __restrict__ sbp,
    bf16_t* __restrict__ R2, bf16_t* __restrict__ R3, bf16_t* __restrict__ R4,
    float* __restrict__ P) {
  const int b = blockIdx.x, c = blockIdx.y;   // c: 0..170
  const int s0 = c * 12;
  const int t = threadIdx.x;
  const int d0 = t * 4;
  const float sb = sbp[0];

  f32x4 h[12];
  float ms[12], p[12];
  f32x4 swv = *(const f32x4*)(sw + d0);
#pragma unroll
  for (int i = 0; i < 12; i++) {
    int s = s0 + i;
    ms[i] = mask01[b * SP + s];
    if (s < SEQ) {
      h[i] = ldbf4(H + ((size_t)b * SEQ + s) * DIM + d0);
    } else {
      h[i].x = h[i].y = h[i].z = h[i].w = 0.f;
    }
    p[i] = h[i].x * swv.x + h[i].y * swv.y + h[i].z * swv.z + h[i].w * swv.w;
  }
  // level means (bf16 out)
#pragma unroll
  for (int j = 0; j < 6; j++) {
    int i0 = 2 * j;
    float cc = ms[i0] + ms[i0 + 1];
    f32x4 sm = h[i0] * ms[i0] + h[i0 + 1] * ms[i0 + 1];
    float sc = cc > 0.f ? 1.f / cc : 0.f;
    stbf4(R2 + ((size_t)b * NB2 + (c * 6 + j)) * DIM + d0, sm * sc);
  }
#pragma unroll
  for (int j = 0; j < 4; j++) {
    int i0 = 3 * j;
    float cc = ms[i0] + ms[i0 + 1] + ms[i0 + 2];
    f32x4 sm = h[i0] * ms[i0] + h[i0 + 1] * ms[i0 + 1] + h[i0 + 2] * ms[i0 + 2];
    float sc = cc > 0.f ? 1.f / cc : 0.f;
    stbf4(R3 + ((size_t)b * NB3 + (c * 4 + j)) * DIM + d0, sm * sc);
  }
#pragma unroll
  for (int j = 0; j < 3; j++) {
    int i0 = 4 * j;
    float cc = ms[i0] + ms[i0 + 1] + ms[i0 + 2] + ms[i0 + 3];
    f32x4 sm = h[i0] * ms[i0] + h[i0 + 1] * ms[i0 + 1] +
               h[i0 + 2] * ms[i0 + 2] + h[i0 + 3] * ms[i0 + 3];
    float sc = cc > 0.f ? 1.f / cc : 0.f;
    stbf4(R4 + ((size_t)b * NB4 + (c * 3 + j)) * DIM + d0, sm * sc);
  }
  // reduce hs = H[s]·score_w across 128 threads (2 waves)
#pragma unroll
  for (int off = 32; off > 0; off >>= 1)
#pragma unroll
    for (int i = 0; i < 12; i++) p[i] += __shfl_down(p[i], off);
  __shared__ float hsw[2][12];
  int lane = t & 63, wv = t >> 6;
  if (lane == 0)
#pragma unroll
    for (int i = 0; i < 12; i++) hsw[wv][i] = p[i];
  __syncthreads();
#define HSUM(i) (hsw[0][i] + hsw[1][i])
  // fused per-position level softmax -> P (all indices stay in-chunk since
  // 12 = lcm(1,2,3,4) and s0 % 12 == 0)
  if (t < 12) {
    int i = t;
    float m1 = ms[i];
    float v1 = HSUM(i) * m1 + sb;
    int i2 = i & ~1;
    float cc2 = ms[i2] + ms[i2 + 1];
    float s2 = HSUM(i2) * ms[i2] + HSUM(i2 + 1) * ms[i2 + 1];
    float v2 = (cc2 > 0.f ? s2 / cc2 : 0.f) + sb;
    int i3 = (i >= 9) ? 9 : (i >= 6) ? 6 : (i >= 3) ? 3 : 0;
    float cc3 = ms[i3] + ms[i3 + 1] + ms[i3 + 2];
    float s3 = HSUM(i3) * ms[i3] + HSUM(i3 + 1) * ms[i3 + 1] +
               HSUM(i3 + 2) * ms[i3 + 2];
    float v3 = (cc3 > 0.f ? s3 / cc3 : 0.f) + sb;
    int i4 = i & ~3;
    float cc4 = ms[i4] + ms[i4 + 1] + ms[i4 + 2] + ms[i4 + 3];
    float s4 = HSUM(i4) * ms[i4] + HSUM(i4 + 1) * ms[i4 + 1] +
               HSUM(i4 + 2) * ms[i4 + 2] + HSUM(i4 + 3) * ms[i4 + 3];
    float v4 = (cc4 > 0.f ? s4 / cc4 : 0.f) + sb;
    const float NEG = -3.0e38f;
    float a1 = m1 > 0.f ? v1 : NEG, a2 = cc2 > 0.f ? v2 : NEG;
    float a3 = cc3 > 0.f ? v3 : NEG, a4 = cc4 > 0.f ? v4 : NEG;
    float mx = fmaxf(fmaxf(a1, a2), fmaxf(a3, a4));
    f32x4 o;
    if (mx <= NEG) {
      o.x = o.y = o.z = o.w = 0.25f;
    } else {
      float e1 = m1 > 0.f ? __expf(v1 - mx) : 0.f;
      float e2 = cc2 > 0.f ? __expf(v2 - mx) : 0.f;
      float e3 = cc3 > 0.f ? __expf(v3 - mx) : 0.f;
      float e4 = cc4 > 0.f ? __expf(v4 - mx) : 0.f;
      float inv = 1.f / (e1 + e2 + e3 + e4);
      o.x = e1 * inv; o.y = e2 * inv; o.z = e3 * inv; o.w = e4 * inv;
    }
    *(f32x4*)(P + ((size_t)b * SP + s0 + i) * 4) = o;
  }
#undef HSUM
}

// ---------------- k5: seq attention (dim 4), 8 j-chunks, zero-Q trick ----
__global__ __launch_bounds__(128) void k5_attn(
    const float* __restrict__ P, const float* __restrict__ mask01,
    float* __restrict__ Wacc) {
  const int b = blockIdx.x, it = blockIdx.y, jc = blockIdx.z;
  const int t = threadIdx.x;
  __shared__ f32x4 Q[JCH];
  __shared__ float c2w[2];
  const int j0 = jc * JCH;
  const int len = (j0 + JCH <= SP) ? JCH : (SP - j0);
  // stage P rows; zero masked rows (then exp(qi·0)=1 exactly, corrected by
  // den -= nmask at the end) — removes per-iter mask load+mul
  float cnt0 = 0.f;
  for (int j = t; j < len; j += 128) {
    f32x4 q = *(const f32x4*)(P + ((size_t)b * SP + j0 + j) * 4);
    float mf = mask01[b * SP + j0 + j];
    if (mf == 0.f) {
      q.x = q.y = q.z = q.w = 0.f;
      cnt0 += 1.f;
    }
    Q[j] = q;
  }
#pragma unroll
  for (int off = 32; off > 0; off >>= 1) cnt0 += __shfl_down(cnt0, off);
  if ((t & 63) == 0) c2w[t >> 6] = cnt0;
  __syncthreads();
  const float nmask = c2w[0] + c2w[1];
  const int i = it * 128 + t;  // 0..2047
  f32x4 qi = *(const f32x4*)(P + ((size_t)b * SP + i) * 4);
  float den = -nmask;
  f32x4 acc; acc.x = acc.y = acc.z = acc.w = 0.f;
  for (int j = 0; j < len; j++) {
    f32x4 pj = Q[j];
    float sim = qi.x * pj.x + qi.y * pj.y + qi.z * pj.z + qi.w * pj.w;
    float e = __expf(sim);
    den += e;
    acc += e * pj;
  }
  float* wp = Wacc + (((size_t)jc * NBATCH + b) * SEQ + i) * 5;
  wp[0] = acc.x; wp[1] = acc.y; wp[2] = acc.z; wp[3] = acc.w; wp[4] = den;
}

// ---------------- k6: combine + weighted reprs + chunk mean -------------
__global__ __launch_bounds__(128) void k6_out(
    const bf16_t* __restrict__ H, const bf16_t* __restrict__ R2,
    const bf16_t* __restrict__ R3, const bf16_t* __restrict__ R4,
    const float* __restrict__ mask01, const float* __restrict__ Wacc,
    float* __restrict__ out, float* __restrict__ omask) {
  const int b = blockIdx.x, l = blockIdx.y;
  const int t = threadIdx.x;
  const int d0 = t * 4;
  __shared__ f32x4 wsh[4];
  __shared__ float msh[4];
  if (t < 32) {
    int si = t >> 3, jc = t & 7;
    int s = l * 4 + si;
    const float* wp = Wacc + (((size_t)jc * NBATCH + b) * SEQ + s) * 5;
    float n0 = wp[0], n1 = wp[1], n2 = wp[2], n3 = wp[3], dn = wp[4];
#pragma unroll
    for (int off = 4; off > 0; off >>= 1) {
      n0 += __shfl_down(n0, off); n1 += __shfl_down(n1, off);
      n2 += __shfl_down(n2, off); n3 += __shfl_down(n3, off);
      dn += __shfl_down(dn, off);
    }
    if ((t & 7) == 0) {
      float inv = dn > 0.f ? 1.f / dn : 0.f;
      f32x4 w; w.x = n0 * inv; w.y = n1 * inv; w.z = n2 * inv; w.w = n3 * inv;
      wsh[si] = w;
      msh[si] = mask01[b * SP + s];
    }
  }
  __syncthreads();
  f32x4 o; o.x = o.y = o.z = o.w = 0.f;
  float cnt = 0.f;
#pragma unroll
  for (int si = 0; si < 4; si++) {
    int s = l * 4 + si;
    float m = msh[si];
    f32x4 w = wsh[si];
    f32x4 r1 = ldbf4(H + ((size_t)b * SEQ + s) * DIM + d0);
    f32x4 r2 = ldbf4(R2 + ((size_t)b * NB2 + (s >> 1)) * DIM + d0);
    f32x4 r3 = ldbf4(R3 + ((size_t)b * NB3 + (s / 3)) * DIM + d0);
    f32x4 r4 = ldbf4(R4 + ((size_t)b * NB4 + (s >> 2)) * DIM + d0);
    o += m * (w.x * r1 + w.y * r2 + w.z * r3 + w.w * r4);
    cnt += m;
  }
  float inv = cnt > 0.f ? 1.f / cnt : 0.f;
  o *= inv;
  *(f32x4*)(out + ((size_t)b * NL + l) * DIM + d0) = o;
  if (t == 0) omask[b * NL + l] = cnt > 0.f ? 1.f : 0.f;
}

// ---------------- launch ----------------
extern "C" void kernel_launch(void* const* d_in, const int* in_sizes, int n_in,
                              void* d_out, int out_size, void* d_ws, size_t ws_size,
                              hipStream_t stream) {
  const int*   x    = (const int*)d_in[0];
  const void*  mraw = d_in[1];
  const float* emb  = (const float*)d_in[2];
  const float* dww  = (const float*)d_in[3];
  const float* dwb  = (const float*)d_in[4];
  const float* pw   = (const float*)d_in[5];
  const float* pwb  = (const float*)d_in[6];
  const float* sw   = (const float*)d_in[7];
  const float* sb   = (const float*)d_in[8];

  char* ws = (char*)d_ws;
  size_t off = 0;
  auto alloc = [&](size_t bytes) {
    size_t o = off;
    off = (off + bytes + 255) & ~(size_t)255;
    return o;
  };
  bf16_t* A    = (bf16_t*)(ws + alloc((size_t)NBATCH * SEQ * DIM * 2));
  bf16_t* H    = (bf16_t*)(ws + alloc((size_t)NBATCH * SEQ * DIM * 2));
  bf16_t* Wt   = (bf16_t*)(ws + alloc((size_t)DIM * DIM * 2));
  bf16_t* R2   = (bf16_t*)(ws + alloc((size_t)NBATCH * NB2 * DIM * 2));
  bf16_t* R3   = (bf16_t*)(ws + alloc((size_t)NBATCH * NB3 * DIM * 2));
  bf16_t* R4   = (bf16_t*)(ws + alloc((size_t)NBATCH * NB4 * DIM * 2));
  float* mask01 = (float*)(ws + alloc((size_t)NBATCH * SP * 4));
  float* P     = (float*)(ws + alloc((size_t)NBATCH * SP * 4 * 4));
  float* Wacc  = (float*)(ws + alloc((size_t)NJC * NBATCH * SEQ * 5 * 4));

  float* out   = (float*)d_out;
  float* omask = out + (size_t)NBATCH * NL * DIM;

  kA_prep<<<GA_WT + GA_MASK + GA_A, 256, 0, stream>>>(pw, Wt, mraw, mask01,
                                                      x, emb, dww, dwb, A);
  k2_gemm<<<512, 256, 0, stream>>>(A, Wt, pwb, H);
  kB_levels<<<dim3(NBATCH, 171), 128, 0, stream>>>(H, mask01, sw, sb,
                                                   R2, R3, R4, P);
  k5_attn<<<dim3(NBATCH, 16, NJC), 128, 0, stream>>>(P, mask01, Wacc);
  k6_out<<<dim3(NBATCH, NL), 128, 0, stream>>>(H, R2, R3, R4, mask01, Wacc,
                                               out, omask);
}

// Round 3
// 141.522 us; speedup vs baseline: 1.1852x; 1.0098x over previous
//
#include <hip/hip_runtime.h>
#include <stdint.h>
#include <stddef.h>

// ---------------- types ----------------
typedef __bf16 bf16_t;
typedef bf16_t bf16x4v __attribute__((ext_vector_type(4)));
typedef bf16_t bf16x8v __attribute__((ext_vector_type(8)));
typedef float  f32x4   __attribute__((ext_vector_type(4)));

#define NBATCH 8
#define SEQ    2048
#define DIM    512
#define SP     2052   // padded seq (mult of 12)
#define NB2    1026
#define NB3    684
#define NB4    513
#define NL     512    // output rows per batch (SEQ/4)
#define NJC    8      // k5 j-chunks
#define JCH    257    // ceil(SP/NJC)

static __device__ __forceinline__ f32x4 ldbf4(const bf16_t* p) {
  bf16x4v v = *(const bf16x4v*)p;
  f32x4 r;
  r.x = (float)v[0]; r.y = (float)v[1]; r.z = (float)v[2]; r.w = (float)v[3];
  return r;
}
static __device__ __forceinline__ void stbf4(bf16_t* p, f32x4 v) {
  bf16x4v o;
  o[0] = (bf16_t)v.x; o[1] = (bf16_t)v.y; o[2] = (bf16_t)v.z; o[3] = (bf16_t)v.w;
  *(bf16x4v*)p = o;
}

static __device__ __forceinline__ void gload_lds16(const void* g, void* l) {
  __builtin_amdgcn_global_load_lds(
      (const __attribute__((address_space(1))) void*)g,
      (__attribute__((address_space(3))) void*)l, 16, 0, 0);
}

// ---------------- kA: fused Wt transpose + mask normalize + depthwise A --
#define GA_WT   256                        // 16x16 tiles of 32x32
#define GA_MASK 65                         // ceil(8*2052 / 256)
#define GA_A    (NBATCH * SEQ / 2)         // 8192 blocks, 2 rows each
__global__ __launch_bounds__(256) void kA_prep(
    const float* __restrict__ pw, bf16_t* __restrict__ Wt,
    const void* __restrict__ mraw, float* __restrict__ mask01,
    const int* __restrict__ x, const float* __restrict__ emb,
    const float* __restrict__ dww, const float* __restrict__ dwb,
    bf16_t* __restrict__ A) {
  const int bx = blockIdx.x, t = threadIdx.x;
  if (bx < GA_WT) {
    // LDS-tiled transpose: pw (K,N) f32 -> Wt (N,K) bf16, 32x32 tiles
    __shared__ float T[32][33];
    int ti = bx >> 4, tj = bx & 15;        // tile k-row, tile n-col
    int r = t >> 3, c0 = (t & 7) * 4;
    f32x4 v = *(const f32x4*)(pw + (size_t)(ti * 32 + r) * DIM + tj * 32 + c0);
    T[c0 + 0][r] = v.x; T[c0 + 1][r] = v.y;
    T[c0 + 2][r] = v.z; T[c0 + 3][r] = v.w;
    __syncthreads();
    bf16x4v o;
    o[0] = (bf16_t)T[r][c0 + 0]; o[1] = (bf16_t)T[r][c0 + 1];
    o[2] = (bf16_t)T[r][c0 + 2]; o[3] = (bf16_t)T[r][c0 + 3];
    *(bf16x4v*)(Wt + (size_t)(tj * 32 + r) * DIM + ti * 32 + c0) = o;
    return;
  }
  if (bx < GA_WT + GA_MASK) {
    int idx = (bx - GA_WT) * 256 + t;
    if (idx >= NBATCH * SP) return;
    int b = idx / SP, s = idx - b * SP;
    const unsigned char* mb = (const unsigned char*)mraw;
    int u8 = 0;
#pragma unroll
    for (int i = 0; i < 64; i++)
      if ((i & 3) != 0 && mb[i] != 0) u8 = 1;
    float v = 0.f;
    if (s < SEQ) {
      int mi = b * SEQ + s;
      int nz = u8 ? (mb[mi] != 0) : (((const int*)mraw)[mi] != 0);
      v = nz ? 1.f : 0.f;
    }
    mask01[idx] = v;
    return;
  }
  // depthwise conv: 2 rows per block
  int rp = bx - (GA_WT + GA_MASK);
  int row = rp * 2 + (t >> 7);             // 0..16383
  int b = row >> 11, s = row & 2047;
  int d0 = (t & 127) * 4;
  f32x4 acc = *(const f32x4*)(dwb + d0);
#pragma unroll
  for (int tt = 0; tt < 4; tt++) {
    int sp = s + tt;
    if (sp < SEQ) {
      int v = x[b * SEQ + sp];
      f32x4 e = *(const f32x4*)(emb + (size_t)v * DIM + d0);
      f32x4 w = *(const f32x4*)(dww + tt * DIM + d0);
      acc += e * w;
    }
  }
  stbf4(A + (size_t)row * DIM + d0, acc);
}

// ---------------- k2: H = A @ Wt^T + pw_b  (bf16 MFMA) ------------------
// BM=64 x BN=128 tiles -> 1024 blocks (4+ resident/CU) so barrier drains in
// one block overlap MFMA in others. acc = 32 VGPR/lane, LDS 12 KB.
#define BM 64
#define BN 128
#define BK 32
__global__ __launch_bounds__(256) void k2_gemm(
    const bf16_t* __restrict__ A, const bf16_t* __restrict__ Bt,
    const float* __restrict__ bias, bf16_t* __restrict__ H) {
  __shared__ __align__(16) bf16_t As[BM * BK];   // 4 KB
  __shared__ __align__(16) bf16_t Bs[BN * BK];   // 8 KB
  const int t = threadIdx.x;
  // XCD swizzle: keep the 4 n-blocks of each m-tile adjacent on one XCD.
  const int bid = blockIdx.x;
  const int xcd = bid & 7, loc = bid >> 3;       // loc 0..127
  const int mt = xcd * 32 + (loc >> 2);          // 0..255
  const int nt = loc & 3;                        // 0..3
  const int m0 = mt * BM, n0 = nt * BN;
  const int lane = t & 63, wave = t >> 6;
  const int wm = (wave & 1) * 32, wn = (wave >> 1) * 64;
  const int mloc = lane & 15, quad = lane >> 4;

  f32x4 acc[2][4] = {};

  char* asd  = (char*)As + t * 16;
  char* bsd1 = (char*)Bs + t * 16;
  char* bsd2 = (char*)Bs + (t + 256) * 16;
  const int ar = t >> 2,           ak = (t & 3) * 8;           // A seg
  const int br1 = t >> 2,          bk1 = (t & 3) * 8;          // B seg 1
  const int br2 = (t + 256) >> 2,  bk2 = (t & 3) * 8;          // B seg 2

  for (int k0 = 0; k0 < 512; k0 += BK) {
    gload_lds16(A + (size_t)(m0 + ar) * DIM + k0 + ak, asd);
    gload_lds16(Bt + (size_t)(n0 + br1) * DIM + k0 + bk1, bsd1);
    gload_lds16(Bt + (size_t)(n0 + br2) * DIM + k0 + bk2, bsd2);
    __syncthreads();
    bf16x8v af[2], bfr[4];
#pragma unroll
    for (int i = 0; i < 2; i++)
      af[i] = *(const bf16x8v*)&As[(wm + i * 16 + mloc) * BK + quad * 8];
#pragma unroll
    for (int i = 0; i < 4; i++)
      bfr[i] = *(const bf16x8v*)&Bs[(wn + i * 16 + mloc) * BK + quad * 8];
#pragma unroll
    for (int mi = 0; mi < 2; mi++)
#pragma unroll
      for (int ni = 0; ni < 4; ni++)
        acc[mi][ni] = __builtin_amdgcn_mfma_f32_16x16x32_bf16(
            af[mi], bfr[ni], acc[mi][ni], 0, 0, 0);
    __syncthreads();
  }
#pragma unroll
  for (int ni = 0; ni < 4; ni++) {
    int col = n0 + wn + ni * 16 + mloc;
    float bv = bias[col];
#pragma unroll
    for (int mi = 0; mi < 2; mi++) {
      int rbase = m0 + wm + mi * 16 + quad * 4;
#pragma unroll
      for (int r = 0; r < 4; r++)
        H[(size_t)(rbase + r) * DIM + col] = (bf16_t)(acc[mi][ni][r] + bv);
    }
  }
}

// ---------------- kB: level means R2/R3/R4 + block scores + P softmax ----
__global__ __launch_bounds__(128) void kB_levels(
    const bf16_t* __restrict__ H, const float* __restrict__ mask01,
    const float* __restrict__ sw, const float* __restrict__ sbp,
    bf16_t* __restrict__ R2, bf16_t* __restrict__ R3, bf16_t* __restrict__ R4,
    float* __restrict__ P) {
  const int b = blockIdx.x, c = blockIdx.y;   // c: 0..170
  const int s0 = c * 12;
  const int t = threadIdx.x;
  const int d0 = t * 4;
  const float sb = sbp[0];

  f32x4 h[12];
  float ms[12], p[12];
  f32x4 swv = *(const f32x4*)(sw + d0);
#pragma unroll
  for (int i = 0; i < 12; i++) {
    int s = s0 + i;
    ms[i] = mask01[b * SP + s];
    if (s < SEQ) {
      h[i] = ldbf4(H + ((size_t)b * SEQ + s) * DIM + d0);
    } else {
      h[i].x = h[i].y = h[i].z = h[i].w = 0.f;
    }
    p[i] = h[i].x * swv.x + h[i].y * swv.y + h[i].z * swv.z + h[i].w * swv.w;
  }
#pragma unroll
  for (int j = 0; j < 6; j++) {
    int i0 = 2 * j;
    float cc = ms[i0] + ms[i0 + 1];
    f32x4 sm = h[i0] * ms[i0] + h[i0 + 1] * ms[i0 + 1];
    float sc = cc > 0.f ? 1.f / cc : 0.f;
    stbf4(R2 + ((size_t)b * NB2 + (c * 6 + j)) * DIM + d0, sm * sc);
  }
#pragma unroll
  for (int j = 0; j < 4; j++) {
    int i0 = 3 * j;
    float cc = ms[i0] + ms[i0 + 1] + ms[i0 + 2];
    f32x4 sm = h[i0] * ms[i0] + h[i0 + 1] * ms[i0 + 1] + h[i0 + 2] * ms[i0 + 2];
    float sc = cc > 0.f ? 1.f / cc : 0.f;
    stbf4(R3 + ((size_t)b * NB3 + (c * 4 + j)) * DIM + d0, sm * sc);
  }
#pragma unroll
  for (int j = 0; j < 3; j++) {
    int i0 = 4 * j;
    float cc = ms[i0] + ms[i0 + 1] + ms[i0 + 2] + ms[i0 + 3];
    f32x4 sm = h[i0] * ms[i0] + h[i0 + 1] * ms[i0 + 1] +
               h[i0 + 2] * ms[i0 + 2] + h[i0 + 3] * ms[i0 + 3];
    float sc = cc > 0.f ? 1.f / cc : 0.f;
    stbf4(R4 + ((size_t)b * NB4 + (c * 3 + j)) * DIM + d0, sm * sc);
  }
#pragma unroll
  for (int off = 32; off > 0; off >>= 1)
#pragma unroll
    for (int i = 0; i < 12; i++) p[i] += __shfl_down(p[i], off);
  __shared__ float hsw[2][12];
  int lane = t & 63, wv = t >> 6;
  if (lane == 0)
#pragma unroll
    for (int i = 0; i < 12; i++) hsw[wv][i] = p[i];
  __syncthreads();
#define HSUM(i) (hsw[0][i] + hsw[1][i])
  if (t < 12) {
    int i = t;
    float m1 = ms[i];
    float v1 = HSUM(i) * m1 + sb;
    int i2 = i & ~1;
    float cc2 = ms[i2] + ms[i2 + 1];
    float s2 = HSUM(i2) * ms[i2] + HSUM(i2 + 1) * ms[i2 + 1];
    float v2 = (cc2 > 0.f ? s2 / cc2 : 0.f) + sb;
    int i3 = (i >= 9) ? 9 : (i >= 6) ? 6 : (i >= 3) ? 3 : 0;
    float cc3 = ms[i3] + ms[i3 + 1] + ms[i3 + 2];
    float s3 = HSUM(i3) * ms[i3] + HSUM(i3 + 1) * ms[i3 + 1] +
               HSUM(i3 + 2) * ms[i3 + 2];
    float v3 = (cc3 > 0.f ? s3 / cc3 : 0.f) + sb;
    int i4 = i & ~3;
    float cc4 = ms[i4] + ms[i4 + 1] + ms[i4 + 2] + ms[i4 + 3];
    float s4 = HSUM(i4) * ms[i4] + HSUM(i4 + 1) * ms[i4 + 1] +
               HSUM(i4 + 2) * ms[i4 + 2] + HSUM(i4 + 3) * ms[i4 + 3];
    float v4 = (cc4 > 0.f ? s4 / cc4 : 0.f) + sb;
    const float NEG = -3.0e38f;
    float a1 = m1 > 0.f ? v1 : NEG, a2 = cc2 > 0.f ? v2 : NEG;
    float a3 = cc3 > 0.f ? v3 : NEG, a4 = cc4 > 0.f ? v4 : NEG;
    float mx = fmaxf(fmaxf(a1, a2), fmaxf(a3, a4));
    f32x4 o;
    if (mx <= NEG) {
      o.x = o.y = o.z = o.w = 0.25f;
    } else {
      float e1 = m1 > 0.f ? __expf(v1 - mx) : 0.f;
      float e2 = cc2 > 0.f ? __expf(v2 - mx) : 0.f;
      float e3 = cc3 > 0.f ? __expf(v3 - mx) : 0.f;
      float e4 = cc4 > 0.f ? __expf(v4 - mx) : 0.f;
      float inv = 1.f / (e1 + e2 + e3 + e4);
      o.x = e1 * inv; o.y = e2 * inv; o.z = e3 * inv; o.w = e4 * inv;
    }
    *(f32x4*)(P + ((size_t)b * SP + s0 + i) * 4) = o;
  }
#undef HSUM
}

// ---------------- k5: seq attention (dim 4), 8 j-chunks, zero-Q trick ----
__global__ __launch_bounds__(128) void k5_attn(
    const float* __restrict__ P, const float* __restrict__ mask01,
    float* __restrict__ Wacc) {
  const int b = blockIdx.x, it = blockIdx.y, jc = blockIdx.z;
  const int t = threadIdx.x;
  __shared__ f32x4 Q[JCH];
  __shared__ float c2w[2];
  const int j0 = jc * JCH;
  const int len = (j0 + JCH <= SP) ? JCH : (SP - j0);
  float cnt0 = 0.f;
  for (int j = t; j < len; j += 128) {
    f32x4 q = *(const f32x4*)(P + ((size_t)b * SP + j0 + j) * 4);
    float mf = mask01[b * SP + j0 + j];
    if (mf == 0.f) {
      q.x = q.y = q.z = q.w = 0.f;
      cnt0 += 1.f;
    }
    Q[j] = q;
  }
#pragma unroll
  for (int off = 32; off > 0; off >>= 1) cnt0 += __shfl_down(cnt0, off);
  if ((t & 63) == 0) c2w[t >> 6] = cnt0;
  __syncthreads();
  const float nmask = c2w[0] + c2w[1];
  const int i = it * 128 + t;  // 0..2047
  f32x4 qi = *(const f32x4*)(P + ((size_t)b * SP + i) * 4);
  float den = -nmask;
  f32x4 acc; acc.x = acc.y = acc.z = acc.w = 0.f;
  for (int j = 0; j < len; j++) {
    f32x4 pj = Q[j];
    float sim = qi.x * pj.x + qi.y * pj.y + qi.z * pj.z + qi.w * pj.w;
    float e = __expf(sim);
    den += e;
    acc += e * pj;
  }
  float* wp = Wacc + (((size_t)jc * NBATCH + b) * SEQ + i) * 5;
  wp[0] = acc.x; wp[1] = acc.y; wp[2] = acc.z; wp[3] = acc.w; wp[4] = den;
}

// ---------------- k6: combine + weighted reprs + chunk mean -------------
__global__ __launch_bounds__(128) void k6_out(
    const bf16_t* __restrict__ H, const bf16_t* __restrict__ R2,
    const bf16_t* __restrict__ R3, const bf16_t* __restrict__ R4,
    const float* __restrict__ mask01, const float* __restrict__ Wacc,
    float* __restrict__ out, float* __restrict__ omask) {
  const int b = blockIdx.x, l = blockIdx.y;
  const int t = threadIdx.x;
  const int d0 = t * 4;
  __shared__ f32x4 wsh[4];
  __shared__ float msh[4];
  if (t < 32) {
    int si = t >> 3, jc = t & 7;
    int s = l * 4 + si;
    const float* wp = Wacc + (((size_t)jc * NBATCH + b) * SEQ + s) * 5;
    float n0 = wp[0], n1 = wp[1], n2 = wp[2], n3 = wp[3], dn = wp[4];
#pragma unroll
    for (int off = 4; off > 0; off >>= 1) {
      n0 += __shfl_down(n0, off); n1 += __shfl_down(n1, off);
      n2 += __shfl_down(n2, off); n3 += __shfl_down(n3, off);
      dn += __shfl_down(dn, off);
    }
    if ((t & 7) == 0) {
      float inv = dn > 0.f ? 1.f / dn : 0.f;
      f32x4 w; w.x = n0 * inv; w.y = n1 * inv; w.z = n2 * inv; w.w = n3 * inv;
      wsh[si] = w;
      msh[si] = mask01[b * SP + s];
    }
  }
  __syncthreads();
  f32x4 o; o.x = o.y = o.z = o.w = 0.f;
  float cnt = 0.f;
#pragma unroll
  for (int si = 0; si < 4; si++) {
    int s = l * 4 + si;
    float m = msh[si];
    f32x4 w = wsh[si];
    f32x4 r1 = ldbf4(H + ((size_t)b * SEQ + s) * DIM + d0);
    f32x4 r2 = ldbf4(R2 + ((size_t)b * NB2 + (s >> 1)) * DIM + d0);
    f32x4 r3 = ldbf4(R3 + ((size_t)b * NB3 + (s / 3)) * DIM + d0);
    f32x4 r4 = ldbf4(R4 + ((size_t)b * NB4 + (s >> 2)) * DIM + d0);
    o += m * (w.x * r1 + w.y * r2 + w.z * r3 + w.w * r4);
    cnt += m;
  }
  float inv = cnt > 0.f ? 1.f / cnt : 0.f;
  o *= inv;
  *(f32x4*)(out + ((size_t)b * NL + l) * DIM + d0) = o;
  if (t == 0) omask[b * NL + l] = cnt > 0.f ? 1.f : 0.f;
}

// ---------------- launch ----------------
extern "C" void kernel_launch(void* const* d_in, const int* in_sizes, int n_in,
                              void* d_out, int out_size, void* d_ws, size_t ws_size,
                              hipStream_t stream) {
  const int*   x    = (const int*)d_in[0];
  const void*  mraw = d_in[1];
  const float* emb  = (const float*)d_in[2];
  const float* dww  = (const float*)d_in[3];
  const float* dwb  = (const float*)d_in[4];
  const float* pw   = (const float*)d_in[5];
  const float* pwb  = (const float*)d_in[6];
  const float* sw   = (const float*)d_in[7];
  const float* sb   = (const float*)d_in[8];

  char* ws = (char*)d_ws;
  size_t off = 0;
  auto alloc = [&](size_t bytes) {
    size_t o = off;
    off = (off + bytes + 255) & ~(size_t)255;
    return o;
  };
  bf16_t* A    = (bf16_t*)(ws + alloc((size_t)NBATCH * SEQ * DIM * 2));
  bf16_t* H    = (bf16_t*)(ws + alloc((size_t)NBATCH * SEQ * DIM * 2));
  bf16_t* Wt   = (bf16_t*)(ws + alloc((size_t)DIM * DIM * 2));
  bf16_t* R2   = (bf16_t*)(ws + alloc((size_t)NBATCH * NB2 * DIM * 2));
  bf16_t* R3   = (bf16_t*)(ws + alloc((size_t)NBATCH * NB3 * DIM * 2));
  bf16_t* R4   = (bf16_t*)(ws + alloc((size_t)NBATCH * NB4 * DIM * 2));
  float* mask01 = (float*)(ws + alloc((size_t)NBATCH * SP * 4));
  float* P     = (float*)(ws + alloc((size_t)NBATCH * SP * 4 * 4));
  float* Wacc  = (float*)(ws + alloc((size_t)NJC * NBATCH * SEQ * 5 * 4));

  float* out   = (float*)d_out;
  float* omask = out + (size_t)NBATCH * NL * DIM;

  kA_prep<<<GA_WT + GA_MASK + GA_A, 256, 0, stream>>>(pw, Wt, mraw, mask01,
                                                      x, emb, dww, dwb, A);
  k2_gemm<<<1024, 256, 0, stream>>>(A, Wt, pwb, H);
  kB_levels<<<dim3(NBATCH, 171), 128, 0, stream>>>(H, mask01, sw, sb,
                                                   R2, R3, R4, P);
  k5_attn<<<dim3(NBATCH, 16, NJC), 128, 0, stream>>>(P, mask01, Wacc);
  k6_out<<<dim3(NBATCH, NL), 128, 0, stream>>>(H, R2, R3, R4, mask01, Wacc,
                                               out, omask);
}